// Round 14
// baseline (303.283 us; speedup 1.0000x reference)
//
#include <hip/hip_runtime.h>
#include <hip/hip_bf16.h>
#include <math.h>

// ---------------------------------------------------------------------------
// DogeCDMoE round 14: EXACT round-13 file (passed, 190.9us) with ONE delta:
// topk selection rewritten from serial butterfly max-extraction (24 x 6-step
// dependent shuffle chains, ~50us hidden cost) to RANK-BASED counting
// selection: sims -> per-wave LDS, each lane counts rank = #{j: s[j]>v ||
// (s[j]==v && j<i)} via broadcast float4 reads (no dependent shuffles);
// rank<8 => winner at slot rank. Ordering == (value desc, index asc) ==
// jax.lax.top_k tie order == previous butterfly => bitwise-identical output.
// ---------------------------------------------------------------------------

#define TOKENS 2048
#define DIM    1024
#define INTER  2048
#define NKEYS  128
#define TOPK   8
#define HEADS  4
#define NINF  -3.4e38f

typedef unsigned short ushort_t;
typedef __attribute__((ext_vector_type(8))) short bf16x8;
typedef __attribute__((ext_vector_type(4))) float f32x4;

__device__ __forceinline__ float bf2f(ushort_t u) {
    unsigned int x = (unsigned int)u << 16;
    float f; __builtin_memcpy(&f, &x, 4); return f;
}
__device__ __forceinline__ ushort_t f2bf_rne(float f) {
    unsigned int x; __builtin_memcpy(&x, &f, 4);
    x += 0x7fffu + ((x >> 16) & 1u);
    return (ushort_t)(x >> 16);
}
__device__ __forceinline__ void gload_lds16(const void* g, void* l) {
    __builtin_amdgcn_global_load_lds(
        (const __attribute__((address_space(1))) unsigned int*)g,
        (__attribute__((address_space(3))) unsigned int*)l, 16, 0, 0);
}

// ---------------- fused f32 -> bf16 (RNE) for all 5 tensors -----------------
__global__ __launch_bounds__(256) void convert_all(
    const float* __restrict__ h,  const float* __restrict__ wq,
    const float* __restrict__ wg, const float* __restrict__ wu,
    const float* __restrict__ wd,
    ushort_t* __restrict__ hb,  ushort_t* __restrict__ wqb,
    ushort_t* __restrict__ wgb, ushort_t* __restrict__ wub,
    ushort_t* __restrict__ wdb) {
    const int i = blockIdx.x * 256 + threadIdx.x;
    const float* src; ushort_t* dst; int off;
    if      (i <  262144) { src = h;  dst = hb;  off = i; }
    else if (i <  294912) { src = wq; dst = wqb; off = i - 262144; }
    else if (i <  557056) { src = wg; dst = wgb; off = i - 294912; }
    else if (i <  819200) { src = wu; dst = wub; off = i - 557056; }
    else                  { src = wd; dst = wdb; off = i - 819200; }
    const float4* p = (const float4*)src + (size_t)off * 2;
    const float4 a = p[0], b = p[1];
    uint4 o;
    o.x = (unsigned)f2bf_rne(a.x) | ((unsigned)f2bf_rne(a.y) << 16);
    o.y = (unsigned)f2bf_rne(a.z) | ((unsigned)f2bf_rne(a.w) << 16);
    o.z = (unsigned)f2bf_rne(b.x) | ((unsigned)f2bf_rne(b.y) << 16);
    o.w = (unsigned)f2bf_rne(b.z) | ((unsigned)f2bf_rne(b.w) << 16);
    ((uint4*)dst)[off] = o;
}

// ---------------- bf16 MFMA GEMM: C[M,N] = A[M,K] @ B[N,K]^T ----------------
// EPI 0: f32 = acc | 1: bf16 = silu(extra_bf16)*acc | 2: f32 = acc+extra_f32
// EPI 3: bf16 = acc   (EPI 2 may have Cout == extra: same-thread in-place add)
template<int BM, int BN, int WR, int WC, int FM, int FN, int EPI>
__global__ __launch_bounds__(256) void mfma_gemm(const ushort_t* __restrict__ A,
                                                 const ushort_t* __restrict__ B,
                                                 const void* __restrict__ extra,
                                                 void* __restrict__ Cout,
                                                 int M, int N, int K) {
    static_assert(WR * WC == 4 && WR * FM * 16 == BM && WC * FN * 16 == BN, "geom");
    __shared__ ushort_t As[BM * 32];
    __shared__ ushort_t Bs[BN * 32];
    const int tid = threadIdx.x;
    const int w = tid >> 6, lane = tid & 63;
    const int wr = w / WC, wc = w % WC;
    const int m0 = blockIdx.y * BM, n0 = blockIdx.x * BN;

    const int srow = (w << 4) + (lane >> 2);
    const int scol = (lane & 3) << 3;
    const ushort_t* Ag = &A[(size_t)(m0 + srow) * K + scol];
    const ushort_t* Bg = &B[(size_t)(n0 + srow) * K + scol];
    ushort_t* Al = &As[w << 9];
    ushort_t* Bl = &Bs[w << 9];

    const int frow = lane & 15;
    const int fcol = (lane >> 4) << 3;
    const ushort_t* Afr = &As[(size_t)(wr * FM * 16 + frow) * 32 + fcol];
    const ushort_t* Bfr = &Bs[(size_t)(wc * FN * 16 + frow) * 32 + fcol];

    f32x4 acc[FM][FN];
#pragma unroll
    for (int i = 0; i < FM; ++i)
#pragma unroll
        for (int j = 0; j < FN; ++j) acc[i][j] = (f32x4){0.f, 0.f, 0.f, 0.f};

    for (int k0 = 0; k0 < K; k0 += 32) {
        __syncthreads();
#pragma unroll
        for (int i = 0; i < BM / 64; ++i)
            gload_lds16(Ag + (size_t)i * 64 * K + k0, Al + i * 2048);
#pragma unroll
        for (int i = 0; i < BN / 64; ++i)
            gload_lds16(Bg + (size_t)i * 64 * K + k0, Bl + i * 2048);
        __syncthreads();

        bf16x8 af[FM], bfv[FN];
#pragma unroll
        for (int i = 0; i < FM; ++i) af[i] = *(const bf16x8*)(Afr + i * 512);
#pragma unroll
        for (int j = 0; j < FN; ++j) bfv[j] = *(const bf16x8*)(Bfr + j * 512);
#pragma unroll
        for (int i = 0; i < FM; ++i)
#pragma unroll
            for (int j = 0; j < FN; ++j)
                acc[i][j] = __builtin_amdgcn_mfma_f32_16x16x32_bf16(
                    af[i], bfv[j], acc[i][j], 0, 0, 0);
    }

    const int crow0 = m0 + wr * FM * 16 + ((lane >> 4) << 2);
    const int ccol0 = n0 + wc * FN * 16 + (lane & 15);
#pragma unroll
    for (int i = 0; i < FM; ++i)
#pragma unroll
        for (int j = 0; j < FN; ++j)
#pragma unroll
            for (int r = 0; r < 4; ++r) {
                const size_t off = (size_t)(crow0 + i * 16 + r) * N + ccol0 + j * 16;
                float v = acc[i][j][r];
                if (EPI == 1) {
                    const float gg = bf2f(((const ushort_t*)extra)[off]);
                    v *= gg / (1.f + __expf(-gg));
                    ((ushort_t*)Cout)[off] = f2bf_rne(v);
                } else if (EPI == 2) {
                    ((float*)Cout)[off] = v + ((const float*)extra)[off];
                } else if (EPI == 3) {
                    ((ushort_t*)Cout)[off] = f2bf_rne(v);
                } else {
                    ((float*)Cout)[off] = v;
                }
            }
}

// ---------------- act[i] = silu(g[i]) * u[i], in-place on u -----------------
__global__ __launch_bounds__(256) void silu_mul_inplace(const ushort_t* __restrict__ g,
                                                        ushort_t* __restrict__ u) {
    const int i = blockIdx.x * 256 + threadIdx.x;   // chunk of 8 bf16
    const uint4 gv = ((const uint4*)g)[i];
    const uint4 uv = ((const uint4*)u)[i];
    const unsigned gw[4] = {gv.x, gv.y, gv.z, gv.w};
    const unsigned uw[4] = {uv.x, uv.y, uv.z, uv.w};
    unsigned ow[4];
#pragma unroll
    for (int j = 0; j < 4; ++j) {
        const float g0 = bf2f((ushort_t)(gw[j] & 0xffff));
        const float g1 = bf2f((ushort_t)(gw[j] >> 16));
        const float u0 = bf2f((ushort_t)(uw[j] & 0xffff));
        const float u1 = bf2f((ushort_t)(uw[j] >> 16));
        const float v0 = g0 / (1.f + __expf(-g0)) * u0;
        const float v1 = g1 / (1.f + __expf(-g1)) * u1;
        ow[j] = (unsigned)f2bf_rne(v0) | ((unsigned)f2bf_rne(v1) << 16);
    }
    ((uint4*)u)[i] = (uint4){ow[0], ow[1], ow[2], ow[3]};
}

// ---------------- topk body: RANK-BASED selection [THE DELTA] ---------------
// Per-head (one wave): sims -> LDS; lane ranks its values against all via
// broadcast float4 reads; rank<8 => winner at slot rank. Ordering =
// (value desc, index asc) = jax.lax.top_k tie order (== old butterfly).
// Softmax accumulation order (rank 0..7) identical to previous code.
__device__ __forceinline__ void topk_body(int t, const float* __restrict__ q,
                                          const float* __restrict__ keys,
                                          int* __restrict__ eidx,
                                          float* __restrict__ ewgt) {
    __shared__ float smx[HEADS][128];
    __shared__ float smy[HEADS][128];
    __shared__ float txv[HEADS][8];
    __shared__ int   txi[HEADS][8];
    __shared__ float tyv[HEADS][8];
    __shared__ int   tyi[HEADS][8];
    __shared__ float comb[HEADS][64];
    __shared__ float tfv[HEADS][8];
    __shared__ int   tfi[HEADS][8];
    const int head = threadIdx.x >> 6;
    const int lane = threadIdx.x & 63;

    // ---- sims (bitwise-identical to previous rounds) ----
    const float4* qx = (const float4*)&q[(size_t)t * 256 + head * 32];
    const float4* qy = (const float4*)&q[(size_t)t * 256 + 128 + head * 32];
    float4 qxv[8], qyv[8];
#pragma unroll
    for (int n = 0; n < 8; ++n) { qxv[n] = qx[n]; qyv[n] = qy[n]; }

    float cx0, cx1, cy0, cy1;
    {
        float s[4];
#pragma unroll
        for (int j = 0; j < 2; ++j) {
            const int k = 2 * lane + j;
            const float4* kx = (const float4*)&keys[(size_t)(((head << 7) | k) * 2 + 0) * 32];
            const float4* ky = (const float4*)&keys[(size_t)(((head << 7) | k) * 2 + 1) * 32];
            float sx = 0.f, sy = 0.f;
#pragma unroll
            for (int n = 0; n < 8; ++n) {
                const float4 a = qxv[n], b = kx[n];
                sx += a.x * b.x + a.y * b.y + a.z * b.z + a.w * b.w;
                const float4 c = qyv[n], d = ky[n];
                sy += c.x * d.x + c.y * d.y + c.z * d.z + c.w * d.w;
            }
            s[j * 2] = sx; s[j * 2 + 1] = sy;
        }
        cx0 = s[0]; cy0 = s[1]; cx1 = s[2]; cy1 = s[3];
    }

    const int i0 = 2 * lane, i1 = 2 * lane + 1;
    smx[head][i0] = cx0; smx[head][i1] = cx1;
    smy[head][i0] = cy0; smy[head][i1] = cy1;
    __syncthreads();

    // ---- rank my x values and y values among their 128 ----
    int cx0r = 0, cx1r = 0, cy0r = 0, cy1r = 0;
#pragma unroll
    for (int j = 0; j < 128; j += 4) {
        const float4 sx = *(const float4*)&smx[head][j];
        cx0r += (sx.x > cx0) | ((sx.x == cx0) & (j + 0 < i0));
        cx0r += (sx.y > cx0) | ((sx.y == cx0) & (j + 1 < i0));
        cx0r += (sx.z > cx0) | ((sx.z == cx0) & (j + 2 < i0));
        cx0r += (sx.w > cx0) | ((sx.w == cx0) & (j + 3 < i0));
        cx1r += (sx.x > cx1) | ((sx.x == cx1) & (j + 0 < i1));
        cx1r += (sx.y > cx1) | ((sx.y == cx1) & (j + 1 < i1));
        cx1r += (sx.z > cx1) | ((sx.z == cx1) & (j + 2 < i1));
        cx1r += (sx.w > cx1) | ((sx.w == cx1) & (j + 3 < i1));
        const float4 sy = *(const float4*)&smy[head][j];
        cy0r += (sy.x > cy0) | ((sy.x == cy0) & (j + 0 < i0));
        cy0r += (sy.y > cy0) | ((sy.y == cy0) & (j + 1 < i0));
        cy0r += (sy.z > cy0) | ((sy.z == cy0) & (j + 2 < i0));
        cy0r += (sy.w > cy0) | ((sy.w == cy0) & (j + 3 < i0));
        cy1r += (sy.x > cy1) | ((sy.x == cy1) & (j + 0 < i1));
        cy1r += (sy.y > cy1) | ((sy.y == cy1) & (j + 1 < i1));
        cy1r += (sy.z > cy1) | ((sy.z == cy1) & (j + 2 < i1));
        cy1r += (sy.w > cy1) | ((sy.w == cy1) & (j + 3 < i1));
    }
    if (cx0r < TOPK) { txv[head][cx0r] = cx0; txi[head][cx0r] = i0; }
    if (cx1r < TOPK) { txv[head][cx1r] = cx1; txi[head][cx1r] = i1; }
    if (cy0r < TOPK) { tyv[head][cy0r] = cy0; tyi[head][cy0r] = i0; }
    if (cy1r < TOPK) { tyv[head][cy1r] = cy1; tyi[head][cy1r] = i1; }
    __syncthreads();

    // ---- cartesian combine: a = lane>>3 (x rank), b = lane&7 (y rank) ----
    const float cv = txv[head][lane >> 3] + tyv[head][lane & 7];
    const int   ci = txi[head][lane >> 3] * NKEYS + tyi[head][lane & 7];
    comb[head][lane] = cv;
    __syncthreads();

    // ---- rank cv among the 64 (tie -> lower position = lane) ----
    int cr = 0;
#pragma unroll
    for (int j = 0; j < 64; j += 4) {
        const float4 s = *(const float4*)&comb[head][j];
        cr += (s.x > cv) | ((s.x == cv) & (j + 0 < lane));
        cr += (s.y > cv) | ((s.y == cv) & (j + 1 < lane));
        cr += (s.z > cv) | ((s.z == cv) & (j + 2 < lane));
        cr += (s.w > cv) | ((s.w == cv) & (j + 3 < lane));
    }
    if (cr < TOPK) { tfv[head][cr] = cv; tfi[head][cr] = ci; }
    __syncthreads();

    // ---- softmax over the 8 winners (same accumulation order as before) ----
    float f[8];
#pragma unroll
    for (int j = 0; j < 8; ++j) f[j] = tfv[head][j];
    float mx = f[0];
#pragma unroll
    for (int j = 1; j < 8; ++j) mx = fmaxf(mx, f[j]);
    float ssum = 0.f;
#pragma unroll
    for (int j = 0; j < 8; ++j) ssum += expf(f[j] - mx);
    if (lane < 8) {
        eidx[t * 32 + head * 8 + lane] = tfi[head][lane];
        ewgt[t * 32 + head * 8 + lane] = expf(f[lane] - mx) / ssum;
    }
}

// ---------------- topk alone (fallback) -------------------------------------
__global__ __launch_bounds__(256) void topk_kernel(const float* __restrict__ q,
                                                   const float* __restrict__ keys,
                                                   int* __restrict__ eidx,
                                                   float* __restrict__ ewgt) {
    topk_body(blockIdx.x, q, keys, eidx, ewgt);
}

// ---------------- topk + expert-table f32->bf16 conversion ------------------
__global__ __launch_bounds__(256) void topk_conv_kernel(
    const float* __restrict__ q, const float* __restrict__ keys,
    int* __restrict__ eidx, float* __restrict__ ewgt,
    const float* __restrict__ de_f32, const float* __restrict__ ue_f32,
    ushort_t* __restrict__ deb, ushort_t* __restrict__ ueb) {
    const int b = blockIdx.x;
    if (b < TOKENS) {
        topk_body(b, q, keys, eidx, ewgt);
        return;
    }
    const int id = b - TOKENS;                       // 0..16383
    const float* src = (id < 8192) ? de_f32 : ue_f32;
    ushort_t*    dst = (id < 8192) ? deb : ueb;
    const size_t off = (size_t)(id & 8191) * 2048 + threadIdx.x * 8;
    const float4* p = (const float4*)(src + off);
    const float4 a = p[0], bb = p[1];
    uint4 o;
    o.x = (unsigned)f2bf_rne(a.x)  | ((unsigned)f2bf_rne(a.y)  << 16);
    o.y = (unsigned)f2bf_rne(a.z)  | ((unsigned)f2bf_rne(a.w)  << 16);
    o.z = (unsigned)f2bf_rne(bb.x) | ((unsigned)f2bf_rne(bb.y) << 16);
    o.w = (unsigned)f2bf_rne(bb.z) | ((unsigned)f2bf_rne(bb.w) << 16);
    *(uint4*)(dst + off) = o;
}

// ---------------- FUSED: gate GEMM + up GEMM + experts blocks ---------------
// BF16T=1: expert tables are bf16 (deb/ueb); 0: f32 (d_in). Same structure.
template<int BF16T>
__global__ __launch_bounds__(256) void fused3_kernel(
    const ushort_t* __restrict__ A,  const ushort_t* __restrict__ Bgate,
    const ushort_t* __restrict__ Bup, ushort_t* __restrict__ G,
    ushort_t* __restrict__ U,
    const float* __restrict__ hs, const void* __restrict__ de_tab,
    const void* __restrict__ ue_tab, const int* __restrict__ eidx,
    const float* __restrict__ ewgt, float* __restrict__ estate) {
    __shared__ __align__(16) char smem[16896];
    const int b = blockIdx.x;
    const int tid = threadIdx.x;
    const int w = tid >> 6, lane = tid & 63;
    const int r6 = b % 6;

    if (r6 == 2 || r6 == 5) {
        const ushort_t* B = (r6 == 2) ? Bgate : Bup;
        ushort_t*      C  = (r6 == 2) ? G : U;
        const int id = b / 6;
        const int m0 = (id >> 4) * 64, n0 = (id & 15) * 128;
        const int N = INTER, K = DIM;
        ushort_t* As = (ushort_t*)smem;             // 4 KB
        ushort_t* Bs = (ushort_t*)(smem + 4096);    // 8 KB
        const int wc = w;                            // WR=1 -> wr=0
        const int srow = (w << 4) + (lane >> 2);
        const int scol = (lane & 3) << 3;
        const ushort_t* Ag = &A[(size_t)(m0 + srow) * K + scol];
        const ushort_t* Bg = &B[(size_t)(n0 + srow) * K + scol];
        ushort_t* Al = &As[w << 9];
        ushort_t* Bl = &Bs[w << 9];
        const int frow = lane & 15;
        const int fcol = (lane >> 4) << 3;
        const ushort_t* Afr = &As[(size_t)frow * 32 + fcol];
        const ushort_t* Bfr = &Bs[(size_t)(wc * 32 + frow) * 32 + fcol];

        f32x4 acc[4][2];
#pragma unroll
        for (int i = 0; i < 4; ++i)
#pragma unroll
            for (int j = 0; j < 2; ++j) acc[i][j] = (f32x4){0.f, 0.f, 0.f, 0.f};

        for (int k0 = 0; k0 < K; k0 += 32) {
            __syncthreads();
            gload_lds16(Ag + k0, Al);
#pragma unroll
            for (int i = 0; i < 2; ++i)
                gload_lds16(Bg + (size_t)i * 64 * K + k0, Bl + i * 2048);
            __syncthreads();

            bf16x8 af[4], bfv[2];
#pragma unroll
            for (int i = 0; i < 4; ++i) af[i] = *(const bf16x8*)(Afr + i * 512);
#pragma unroll
            for (int j = 0; j < 2; ++j) bfv[j] = *(const bf16x8*)(Bfr + j * 512);
#pragma unroll
            for (int i = 0; i < 4; ++i)
#pragma unroll
                for (int j = 0; j < 2; ++j)
                    acc[i][j] = __builtin_amdgcn_mfma_f32_16x16x32_bf16(
                        af[i], bfv[j], acc[i][j], 0, 0, 0);
        }

        const int crow0 = m0 + ((lane >> 4) << 2);
        const int ccol0 = n0 + wc * 32 + (lane & 15);
#pragma unroll
        for (int i = 0; i < 4; ++i)
#pragma unroll
            for (int j = 0; j < 2; ++j)
#pragma unroll
                for (int r = 0; r < 4; ++r) {
                    const size_t off = (size_t)(crow0 + i * 16 + r) * N + ccol0 + j * 16;
                    C[off] = f2bf_rne(acc[i][j][r]);
                }
    } else {
        const int t = (b / 6) * 4 + r6 - (r6 > 2 ? 1 : 0);
        float4 (*partial)[256] = (float4(*)[256])smem;      // 16 KB
        int*   eid = (int*)(smem + 16384);                  // 128 B
        float* wl  = (float*)(smem + 16512);                // 128 B

        if (tid < 32) { eid[tid] = eidx[t * 32 + tid]; wl[tid] = ewgt[t * 32 + tid]; }

        const float4* hs4 = (const float4*)hs + (size_t)t * 256;
        float4 h[4];
#pragma unroll
        for (int i = 0; i < 4; ++i) h[i] = hs4[i * 64 + lane];
        __syncthreads();

        float4 acc[4];
#pragma unroll
        for (int i = 0; i < 4; ++i) acc[i] = (float4){0.f, 0.f, 0.f, 0.f};

        if (BF16T) {
            const ushort4* de4 = (const ushort4*)de_tab;
            const ushort4* ue4 = (const ushort4*)ue_tab;
            ushort4 d[4], u[4], nd[4], nu[4];
            {
                const size_t bb = (size_t)eid[w * 8] * 256;
#pragma unroll
                for (int i = 0; i < 4; ++i) { d[i] = de4[bb + i * 64 + lane]; u[i] = ue4[bb + i * 64 + lane]; }
            }
#pragma unroll
            for (int jj = 0; jj < 8; ++jj) {
                if (jj < 7) {
                    const size_t bb = (size_t)eid[w * 8 + jj + 1] * 256;
#pragma unroll
                    for (int i = 0; i < 4; ++i) { nd[i] = de4[bb + i * 64 + lane]; nu[i] = ue4[bb + i * 64 + lane]; }
                }
                float s = 0.f;
#pragma unroll
                for (int i = 0; i < 4; ++i)
                    s += h[i].x * bf2f(d[i].x) + h[i].y * bf2f(d[i].y)
                       + h[i].z * bf2f(d[i].z) + h[i].w * bf2f(d[i].w);
#pragma unroll
                for (int m = 1; m < 64; m <<= 1) s += __shfl_xor(s, m);
                const float c = (s / (1.f + __expf(-s))) * wl[w * 8 + jj];
#pragma unroll
                for (int i = 0; i < 4; ++i) {
                    acc[i].x += c * bf2f(u[i].x); acc[i].y += c * bf2f(u[i].y);
                    acc[i].z += c * bf2f(u[i].z); acc[i].w += c * bf2f(u[i].w);
                }
                if (jj < 7) {
#pragma unroll
                    for (int i = 0; i < 4; ++i) { d[i] = nd[i]; u[i] = nu[i]; }
                }
            }
        } else {
            const float4* de4 = (const float4*)de_tab;
            const float4* ue4 = (const float4*)ue_tab;
            float4 d[4], u[4], nd[4], nu[4];
            {
                const size_t bb = (size_t)eid[w * 8] * 256;
#pragma unroll
                for (int i = 0; i < 4; ++i) { d[i] = de4[bb + i * 64 + lane]; u[i] = ue4[bb + i * 64 + lane]; }
            }
#pragma unroll
            for (int jj = 0; jj < 8; ++jj) {
                if (jj < 7) {
                    const size_t bb = (size_t)eid[w * 8 + jj + 1] * 256;
#pragma unroll
                    for (int i = 0; i < 4; ++i) { nd[i] = de4[bb + i * 64 + lane]; nu[i] = ue4[bb + i * 64 + lane]; }
                }
                float s = 0.f;
#pragma unroll
                for (int i = 0; i < 4; ++i)
                    s += h[i].x * d[i].x + h[i].y * d[i].y + h[i].z * d[i].z + h[i].w * d[i].w;
#pragma unroll
                for (int m = 1; m < 64; m <<= 1) s += __shfl_xor(s, m);
                const float c = (s / (1.f + __expf(-s))) * wl[w * 8 + jj];
#pragma unroll
                for (int i = 0; i < 4; ++i) {
                    acc[i].x += c * u[i].x; acc[i].y += c * u[i].y;
                    acc[i].z += c * u[i].z; acc[i].w += c * u[i].w;
                }
                if (jj < 7) {
#pragma unroll
                    for (int i = 0; i < 4; ++i) { d[i] = nd[i]; u[i] = nu[i]; }
                }
            }
        }

#pragma unroll
        for (int i = 0; i < 4; ++i) partial[w][i * 64 + lane] = acc[i];
        __syncthreads();

        const float4 p0 = partial[0][tid], p1 = partial[1][tid];
        const float4 p2 = partial[2][tid], p3 = partial[3][tid];
        float4 o;
        o.x = p0.x + p1.x + p2.x + p3.x;
        o.y = p0.y + p1.y + p2.y + p3.y;
        o.z = p0.z + p1.z + p2.z + p3.z;
        o.w = p0.w + p1.w + p2.w + p3.w;
        ((float4*)estate)[(size_t)t * 256 + tid] = o;
    }
}

// ---------------------------------------------------------------------------
extern "C" void kernel_launch(void* const* d_in, const int* in_sizes, int n_in,
                              void* d_out, int out_size, void* d_ws, size_t ws_size,
                              hipStream_t stream) {
    (void)in_sizes; (void)n_in; (void)out_size;
    const float* hidden = (const float*)d_in[0];
    const float* wq     = (const float*)d_in[1];
    const float* keys   = (const float*)d_in[2];
    const float* down_e = (const float*)d_in[3];
    const float* up_e   = (const float*)d_in[4];
    const float* wgate  = (const float*)d_in[5];
    const float* wup    = (const float*)d_in[6];
    const float* wdown  = (const float*)d_in[7];
    float* out = (float*)d_out;
    char* ws = (char*)d_ws;

    // workspace layout: EXACT round-13 (passed).
    ushort_t* hb  = (ushort_t*)(ws);                     // 4 MB
    ushort_t* wqb = (ushort_t*)(ws + (4u << 20));        // 0.5 MB
    ushort_t* wgb = (ushort_t*)(ws + (4608u << 10));     // 4 MB
    ushort_t* wub = (ushort_t*)(ws + (8704u << 10));     // 4 MB
    ushort_t* wdb = (ushort_t*)(ws + (12800u << 10));    // 4 MB
    float*    q   = (float*)   (ws + (16896u << 10));    // 2 MB
    ushort_t* act = (ushort_t*)(ws + (18944u << 10));    // 8 MB (raw u, then act)
    ushort_t* g   = (ushort_t*)(ws + (27136u << 10));    // 8 MB
    float*    wgt = (float*)   (ws + (35328u << 10));    // 0.25 MB
    int*     eidx = (int*)     (ws + (35584u << 10));    // 0.25 MB  (end 35.84 MB)
    ushort_t* deb = (ushort_t*)(ws + 36700160u);         // 32 MB
    ushort_t* ueb = (ushort_t*)(ws + 70254592u);         // 32 MB (end 103809024)
    float* estate = out;                                 // 8 MB, in d_out

    const bool bf16t = ws_size >= 103809024ull;          // host-side, deterministic

    convert_all<<<4224, 256, 0, stream>>>(hidden, wq, wgate, wup, wdown,
                                          hb, wqb, wgb, wub, wdb);

    // 1) q = hidden @ wq^T  (2048 x 256 x 1024), f32 out for routing
    mfma_gemm<64, 64, 2, 2, 2, 2, 0><<<dim3(4, 32), 256, 0, stream>>>(
        hb, wqb, nullptr, q, TOKENS, 256, DIM);

    if (bf16t) {
        // 2) routing (rank-based) + expert-table bf16 conversion
        topk_conv_kernel<<<TOKENS + 16384, 256, 0, stream>>>(
            q, keys, eidx, wgt, down_e, up_e, deb, ueb);
        // 3+4+5 FUSED) g/u GEMMs || experts (bf16 tables) -> out
        fused3_kernel<1><<<3072, 256, 0, stream>>>(
            hb, wgb, wub, g, act, hidden, deb, ueb, eidx, wgt, estate);
    } else {
        // fallback: R12 path with rank-based topk
        topk_kernel<<<TOKENS, 256, 0, stream>>>(q, keys, eidx, wgt);
        fused3_kernel<0><<<3072, 256, 0, stream>>>(
            hb, wgb, wub, g, act, hidden, down_e, up_e, eidx, wgt, estate);
    }

    // 4b) act = silu(g) * u, in-place on the u buffer
    silu_mul_inplace<<<2048, 256, 0, stream>>>(g, act);
    // 6) out = act @ wdown^T + out(=estate)
    mfma_gemm<64, 64, 2, 2, 2, 2, 2><<<dim3(16, 32), 256, 0, stream>>>(
        act, wdb, estate, out, TOKENS, DIM, INTER);
}

// Round 15
// 283.757 us; speedup vs baseline: 1.0688x; 1.0688x over previous
//
#include <hip/hip_runtime.h>
#include <hip/hip_bf16.h>
#include <math.h>

// ---------------------------------------------------------------------------
// DogeCDMoE round 15: fixes R14's regression. R14 counters: fusing the
// rank-topk (VGPR 136, 6KB LDS) with the table conversion dragged the
// 16384 streaming blocks to 11% occupancy -> 0.33 TB/s. Fix: DECOUPLE.
// topk_kernel (rank-based, verified bitwise-identical in R14) runs alone;
// conv_tables is a separate minimal streaming kernel (VGPR ~32, no LDS,
// full occupancy). Everything else byte-identical to R13/R14.
// ---------------------------------------------------------------------------

#define TOKENS 2048
#define DIM    1024
#define INTER  2048
#define NKEYS  128
#define TOPK   8
#define HEADS  4
#define NINF  -3.4e38f

typedef unsigned short ushort_t;
typedef __attribute__((ext_vector_type(8))) short bf16x8;
typedef __attribute__((ext_vector_type(4))) float f32x4;

__device__ __forceinline__ float bf2f(ushort_t u) {
    unsigned int x = (unsigned int)u << 16;
    float f; __builtin_memcpy(&f, &x, 4); return f;
}
__device__ __forceinline__ ushort_t f2bf_rne(float f) {
    unsigned int x; __builtin_memcpy(&x, &f, 4);
    x += 0x7fffu + ((x >> 16) & 1u);
    return (ushort_t)(x >> 16);
}
__device__ __forceinline__ void gload_lds16(const void* g, void* l) {
    __builtin_amdgcn_global_load_lds(
        (const __attribute__((address_space(1))) unsigned int*)g,
        (__attribute__((address_space(3))) unsigned int*)l, 16, 0, 0);
}

// ---------------- fused f32 -> bf16 (RNE) for all 5 tensors -----------------
__global__ __launch_bounds__(256) void convert_all(
    const float* __restrict__ h,  const float* __restrict__ wq,
    const float* __restrict__ wg, const float* __restrict__ wu,
    const float* __restrict__ wd,
    ushort_t* __restrict__ hb,  ushort_t* __restrict__ wqb,
    ushort_t* __restrict__ wgb, ushort_t* __restrict__ wub,
    ushort_t* __restrict__ wdb) {
    const int i = blockIdx.x * 256 + threadIdx.x;
    const float* src; ushort_t* dst; int off;
    if      (i <  262144) { src = h;  dst = hb;  off = i; }
    else if (i <  294912) { src = wq; dst = wqb; off = i - 262144; }
    else if (i <  557056) { src = wg; dst = wgb; off = i - 294912; }
    else if (i <  819200) { src = wu; dst = wub; off = i - 557056; }
    else                  { src = wd; dst = wdb; off = i - 819200; }
    const float4* p = (const float4*)src + (size_t)off * 2;
    const float4 a = p[0], b = p[1];
    uint4 o;
    o.x = (unsigned)f2bf_rne(a.x) | ((unsigned)f2bf_rne(a.y) << 16);
    o.y = (unsigned)f2bf_rne(a.z) | ((unsigned)f2bf_rne(a.w) << 16);
    o.z = (unsigned)f2bf_rne(b.x) | ((unsigned)f2bf_rne(b.y) << 16);
    o.w = (unsigned)f2bf_rne(b.z) | ((unsigned)f2bf_rne(b.w) << 16);
    ((uint4*)dst)[off] = o;
}

// ---------------- expert-table f32 -> bf16, standalone streaming [DELTA] ----
// 16384 blocks x 256 threads x 8 elems: first 8192 blocks -> deb, rest -> ueb.
__global__ __launch_bounds__(256) void conv_tables(
    const float* __restrict__ de_f32, const float* __restrict__ ue_f32,
    ushort_t* __restrict__ deb, ushort_t* __restrict__ ueb) {
    const int id = blockIdx.x;                       // 0..16383
    const float* src = (id < 8192) ? de_f32 : ue_f32;
    ushort_t*    dst = (id < 8192) ? deb : ueb;
    const size_t off = (size_t)(id & 8191) * 2048 + threadIdx.x * 8;
    const float4* p = (const float4*)(src + off);
    const float4 a = p[0], b = p[1];
    uint4 o;
    o.x = (unsigned)f2bf_rne(a.x) | ((unsigned)f2bf_rne(a.y) << 16);
    o.y = (unsigned)f2bf_rne(a.z) | ((unsigned)f2bf_rne(a.w) << 16);
    o.z = (unsigned)f2bf_rne(b.x) | ((unsigned)f2bf_rne(b.y) << 16);
    o.w = (unsigned)f2bf_rne(b.z) | ((unsigned)f2bf_rne(b.w) << 16);
    *(uint4*)(dst + off) = o;
}

// ---------------- bf16 MFMA GEMM: C[M,N] = A[M,K] @ B[N,K]^T ----------------
// EPI 0: f32 = acc | 1: bf16 = silu(extra_bf16)*acc | 2: f32 = acc+extra_f32
// EPI 3: bf16 = acc   (EPI 2 may have Cout == extra: same-thread in-place add)
template<int BM, int BN, int WR, int WC, int FM, int FN, int EPI>
__global__ __launch_bounds__(256) void mfma_gemm(const ushort_t* __restrict__ A,
                                                 const ushort_t* __restrict__ B,
                                                 const void* __restrict__ extra,
                                                 void* __restrict__ Cout,
                                                 int M, int N, int K) {
    static_assert(WR * WC == 4 && WR * FM * 16 == BM && WC * FN * 16 == BN, "geom");
    __shared__ ushort_t As[BM * 32];
    __shared__ ushort_t Bs[BN * 32];
    const int tid = threadIdx.x;
    const int w = tid >> 6, lane = tid & 63;
    const int wr = w / WC, wc = w % WC;
    const int m0 = blockIdx.y * BM, n0 = blockIdx.x * BN;

    const int srow = (w << 4) + (lane >> 2);
    const int scol = (lane & 3) << 3;
    const ushort_t* Ag = &A[(size_t)(m0 + srow) * K + scol];
    const ushort_t* Bg = &B[(size_t)(n0 + srow) * K + scol];
    ushort_t* Al = &As[w << 9];
    ushort_t* Bl = &Bs[w << 9];

    const int frow = lane & 15;
    const int fcol = (lane >> 4) << 3;
    const ushort_t* Afr = &As[(size_t)(wr * FM * 16 + frow) * 32 + fcol];
    const ushort_t* Bfr = &Bs[(size_t)(wc * FN * 16 + frow) * 32 + fcol];

    f32x4 acc[FM][FN];
#pragma unroll
    for (int i = 0; i < FM; ++i)
#pragma unroll
        for (int j = 0; j < FN; ++j) acc[i][j] = (f32x4){0.f, 0.f, 0.f, 0.f};

    for (int k0 = 0; k0 < K; k0 += 32) {
        __syncthreads();
#pragma unroll
        for (int i = 0; i < BM / 64; ++i)
            gload_lds16(Ag + (size_t)i * 64 * K + k0, Al + i * 2048);
#pragma unroll
        for (int i = 0; i < BN / 64; ++i)
            gload_lds16(Bg + (size_t)i * 64 * K + k0, Bl + i * 2048);
        __syncthreads();

        bf16x8 af[FM], bfv[FN];
#pragma unroll
        for (int i = 0; i < FM; ++i) af[i] = *(const bf16x8*)(Afr + i * 512);
#pragma unroll
        for (int j = 0; j < FN; ++j) bfv[j] = *(const bf16x8*)(Bfr + j * 512);
#pragma unroll
        for (int i = 0; i < FM; ++i)
#pragma unroll
            for (int j = 0; j < FN; ++j)
                acc[i][j] = __builtin_amdgcn_mfma_f32_16x16x32_bf16(
                    af[i], bfv[j], acc[i][j], 0, 0, 0);
    }

    const int crow0 = m0 + wr * FM * 16 + ((lane >> 4) << 2);
    const int ccol0 = n0 + wc * FN * 16 + (lane & 15);
#pragma unroll
    for (int i = 0; i < FM; ++i)
#pragma unroll
        for (int j = 0; j < FN; ++j)
#pragma unroll
            for (int r = 0; r < 4; ++r) {
                const size_t off = (size_t)(crow0 + i * 16 + r) * N + ccol0 + j * 16;
                float v = acc[i][j][r];
                if (EPI == 1) {
                    const float gg = bf2f(((const ushort_t*)extra)[off]);
                    v *= gg / (1.f + __expf(-gg));
                    ((ushort_t*)Cout)[off] = f2bf_rne(v);
                } else if (EPI == 2) {
                    ((float*)Cout)[off] = v + ((const float*)extra)[off];
                } else if (EPI == 3) {
                    ((ushort_t*)Cout)[off] = f2bf_rne(v);
                } else {
                    ((float*)Cout)[off] = v;
                }
            }
}

// ---------------- act[i] = silu(g[i]) * u[i], in-place on u -----------------
__global__ __launch_bounds__(256) void silu_mul_inplace(const ushort_t* __restrict__ g,
                                                        ushort_t* __restrict__ u) {
    const int i = blockIdx.x * 256 + threadIdx.x;   // chunk of 8 bf16
    const uint4 gv = ((const uint4*)g)[i];
    const uint4 uv = ((const uint4*)u)[i];
    const unsigned gw[4] = {gv.x, gv.y, gv.z, gv.w};
    const unsigned uw[4] = {uv.x, uv.y, uv.z, uv.w};
    unsigned ow[4];
#pragma unroll
    for (int j = 0; j < 4; ++j) {
        const float g0 = bf2f((ushort_t)(gw[j] & 0xffff));
        const float g1 = bf2f((ushort_t)(gw[j] >> 16));
        const float u0 = bf2f((ushort_t)(uw[j] & 0xffff));
        const float u1 = bf2f((ushort_t)(uw[j] >> 16));
        const float v0 = g0 / (1.f + __expf(-g0)) * u0;
        const float v1 = g1 / (1.f + __expf(-g1)) * u1;
        ow[j] = (unsigned)f2bf_rne(v0) | ((unsigned)f2bf_rne(v1) << 16);
    }
    ((uint4*)u)[i] = (uint4){ow[0], ow[1], ow[2], ow[3]};
}

// ---------------- topk: RANK-BASED selection (verified bitwise in R14) ------
__global__ __launch_bounds__(256) void topk_kernel(const float* __restrict__ q,
                                                   const float* __restrict__ keys,
                                                   int* __restrict__ eidx,
                                                   float* __restrict__ ewgt) {
    __shared__ float smx[HEADS][128];
    __shared__ float smy[HEADS][128];
    __shared__ float txv[HEADS][8];
    __shared__ int   txi[HEADS][8];
    __shared__ float tyv[HEADS][8];
    __shared__ int   tyi[HEADS][8];
    __shared__ float comb[HEADS][64];
    __shared__ float tfv[HEADS][8];
    __shared__ int   tfi[HEADS][8];
    const int t = blockIdx.x;
    const int head = threadIdx.x >> 6;
    const int lane = threadIdx.x & 63;

    // ---- sims (bitwise-identical to previous rounds) ----
    const float4* qx = (const float4*)&q[(size_t)t * 256 + head * 32];
    const float4* qy = (const float4*)&q[(size_t)t * 256 + 128 + head * 32];
    float4 qxv[8], qyv[8];
#pragma unroll
    for (int n = 0; n < 8; ++n) { qxv[n] = qx[n]; qyv[n] = qy[n]; }

    float cx0, cx1, cy0, cy1;
    {
        float s[4];
#pragma unroll
        for (int j = 0; j < 2; ++j) {
            const int k = 2 * lane + j;
            const float4* kx = (const float4*)&keys[(size_t)(((head << 7) | k) * 2 + 0) * 32];
            const float4* ky = (const float4*)&keys[(size_t)(((head << 7) | k) * 2 + 1) * 32];
            float sx = 0.f, sy = 0.f;
#pragma unroll
            for (int n = 0; n < 8; ++n) {
                const float4 a = qxv[n], b = kx[n];
                sx += a.x * b.x + a.y * b.y + a.z * b.z + a.w * b.w;
                const float4 c = qyv[n], d = ky[n];
                sy += c.x * d.x + c.y * d.y + c.z * d.z + c.w * d.w;
            }
            s[j * 2] = sx; s[j * 2 + 1] = sy;
        }
        cx0 = s[0]; cy0 = s[1]; cx1 = s[2]; cy1 = s[3];
    }

    const int i0 = 2 * lane, i1 = 2 * lane + 1;
    smx[head][i0] = cx0; smx[head][i1] = cx1;
    smy[head][i0] = cy0; smy[head][i1] = cy1;
    __syncthreads();

    int cx0r = 0, cx1r = 0, cy0r = 0, cy1r = 0;
#pragma unroll
    for (int j = 0; j < 128; j += 4) {
        const float4 sx = *(const float4*)&smx[head][j];
        cx0r += (sx.x > cx0) | ((sx.x == cx0) & (j + 0 < i0));
        cx0r += (sx.y > cx0) | ((sx.y == cx0) & (j + 1 < i0));
        cx0r += (sx.z > cx0) | ((sx.z == cx0) & (j + 2 < i0));
        cx0r += (sx.w > cx0) | ((sx.w == cx0) & (j + 3 < i0));
        cx1r += (sx.x > cx1) | ((sx.x == cx1) & (j + 0 < i1));
        cx1r += (sx.y > cx1) | ((sx.y == cx1) & (j + 1 < i1));
        cx1r += (sx.z > cx1) | ((sx.z == cx1) & (j + 2 < i1));
        cx1r += (sx.w > cx1) | ((sx.w == cx1) & (j + 3 < i1));
        const float4 sy = *(const float4*)&smy[head][j];
        cy0r += (sy.x > cy0) | ((sy.x == cy0) & (j + 0 < i0));
        cy0r += (sy.y > cy0) | ((sy.y == cy0) & (j + 1 < i0));
        cy0r += (sy.z > cy0) | ((sy.z == cy0) & (j + 2 < i0));
        cy0r += (sy.w > cy0) | ((sy.w == cy0) & (j + 3 < i0));
        cy1r += (sy.x > cy1) | ((sy.x == cy1) & (j + 0 < i1));
        cy1r += (sy.y > cy1) | ((sy.y == cy1) & (j + 1 < i1));
        cy1r += (sy.z > cy1) | ((sy.z == cy1) & (j + 2 < i1));
        cy1r += (sy.w > cy1) | ((sy.w == cy1) & (j + 3 < i1));
    }
    if (cx0r < TOPK) { txv[head][cx0r] = cx0; txi[head][cx0r] = i0; }
    if (cx1r < TOPK) { txv[head][cx1r] = cx1; txi[head][cx1r] = i1; }
    if (cy0r < TOPK) { tyv[head][cy0r] = cy0; tyi[head][cy0r] = i0; }
    if (cy1r < TOPK) { tyv[head][cy1r] = cy1; tyi[head][cy1r] = i1; }
    __syncthreads();

    const float cv = txv[head][lane >> 3] + tyv[head][lane & 7];
    const int   ci = txi[head][lane >> 3] * NKEYS + tyi[head][lane & 7];
    comb[head][lane] = cv;
    __syncthreads();

    int cr = 0;
#pragma unroll
    for (int j = 0; j < 64; j += 4) {
        const float4 s = *(const float4*)&comb[head][j];
        cr += (s.x > cv) | ((s.x == cv) & (j + 0 < lane));
        cr += (s.y > cv) | ((s.y == cv) & (j + 1 < lane));
        cr += (s.z > cv) | ((s.z == cv) & (j + 2 < lane));
        cr += (s.w > cv) | ((s.w == cv) & (j + 3 < lane));
    }
    if (cr < TOPK) { tfv[head][cr] = cv; tfi[head][cr] = ci; }
    __syncthreads();

    float f[8];
#pragma unroll
    for (int j = 0; j < 8; ++j) f[j] = tfv[head][j];
    float mx = f[0];
#pragma unroll
    for (int j = 1; j < 8; ++j) mx = fmaxf(mx, f[j]);
    float ssum = 0.f;
#pragma unroll
    for (int j = 0; j < 8; ++j) ssum += expf(f[j] - mx);
    if (lane < 8) {
        eidx[t * 32 + head * 8 + lane] = tfi[head][lane];
        ewgt[t * 32 + head * 8 + lane] = expf(f[lane] - mx) / ssum;
    }
}

// ---------------- FUSED: gate GEMM + up GEMM + experts blocks ---------------
// BF16T=1: expert tables are bf16 (deb/ueb); 0: f32 (d_in). Same structure.
template<int BF16T>
__global__ __launch_bounds__(256) void fused3_kernel(
    const ushort_t* __restrict__ A,  const ushort_t* __restrict__ Bgate,
    const ushort_t* __restrict__ Bup, ushort_t* __restrict__ G,
    ushort_t* __restrict__ U,
    const float* __restrict__ hs, const void* __restrict__ de_tab,
    const void* __restrict__ ue_tab, const int* __restrict__ eidx,
    const float* __restrict__ ewgt, float* __restrict__ estate) {
    __shared__ __align__(16) char smem[16896];
    const int b = blockIdx.x;
    const int tid = threadIdx.x;
    const int w = tid >> 6, lane = tid & 63;
    const int r6 = b % 6;

    if (r6 == 2 || r6 == 5) {
        const ushort_t* B = (r6 == 2) ? Bgate : Bup;
        ushort_t*      C  = (r6 == 2) ? G : U;
        const int id = b / 6;
        const int m0 = (id >> 4) * 64, n0 = (id & 15) * 128;
        const int N = INTER, K = DIM;
        ushort_t* As = (ushort_t*)smem;             // 4 KB
        ushort_t* Bs = (ushort_t*)(smem + 4096);    // 8 KB
        const int wc = w;                            // WR=1 -> wr=0
        const int srow = (w << 4) + (lane >> 2);
        const int scol = (lane & 3) << 3;
        const ushort_t* Ag = &A[(size_t)(m0 + srow) * K + scol];
        const ushort_t* Bg = &B[(size_t)(n0 + srow) * K + scol];
        ushort_t* Al = &As[w << 9];
        ushort_t* Bl = &Bs[w << 9];
        const int frow = lane & 15;
        const int fcol = (lane >> 4) << 3;
        const ushort_t* Afr = &As[(size_t)frow * 32 + fcol];
        const ushort_t* Bfr = &Bs[(size_t)(wc * 32 + frow) * 32 + fcol];

        f32x4 acc[4][2];
#pragma unroll
        for (int i = 0; i < 4; ++i)
#pragma unroll
            for (int j = 0; j < 2; ++j) acc[i][j] = (f32x4){0.f, 0.f, 0.f, 0.f};

        for (int k0 = 0; k0 < K; k0 += 32) {
            __syncthreads();
            gload_lds16(Ag + k0, Al);
#pragma unroll
            for (int i = 0; i < 2; ++i)
                gload_lds16(Bg + (size_t)i * 64 * K + k0, Bl + i * 2048);
            __syncthreads();

            bf16x8 af[4], bfv[2];
#pragma unroll
            for (int i = 0; i < 4; ++i) af[i] = *(const bf16x8*)(Afr + i * 512);
#pragma unroll
            for (int j = 0; j < 2; ++j) bfv[j] = *(const bf16x8*)(Bfr + j * 512);
#pragma unroll
            for (int i = 0; i < 4; ++i)
#pragma unroll
                for (int j = 0; j < 2; ++j)
                    acc[i][j] = __builtin_amdgcn_mfma_f32_16x16x32_bf16(
                        af[i], bfv[j], acc[i][j], 0, 0, 0);
        }

        const int crow0 = m0 + ((lane >> 4) << 2);
        const int ccol0 = n0 + wc * 32 + (lane & 15);
#pragma unroll
        for (int i = 0; i < 4; ++i)
#pragma unroll
            for (int j = 0; j < 2; ++j)
#pragma unroll
                for (int r = 0; r < 4; ++r) {
                    const size_t off = (size_t)(crow0 + i * 16 + r) * N + ccol0 + j * 16;
                    C[off] = f2bf_rne(acc[i][j][r]);
                }
    } else {
        const int t = (b / 6) * 4 + r6 - (r6 > 2 ? 1 : 0);
        float4 (*partial)[256] = (float4(*)[256])smem;      // 16 KB
        int*   eid = (int*)(smem + 16384);                  // 128 B
        float* wl  = (float*)(smem + 16512);                // 128 B

        if (tid < 32) { eid[tid] = eidx[t * 32 + tid]; wl[tid] = ewgt[t * 32 + tid]; }

        const float4* hs4 = (const float4*)hs + (size_t)t * 256;
        float4 h[4];
#pragma unroll
        for (int i = 0; i < 4; ++i) h[i] = hs4[i * 64 + lane];
        __syncthreads();

        float4 acc[4];
#pragma unroll
        for (int i = 0; i < 4; ++i) acc[i] = (float4){0.f, 0.f, 0.f, 0.f};

        if (BF16T) {
            const ushort4* de4 = (const ushort4*)de_tab;
            const ushort4* ue4 = (const ushort4*)ue_tab;
            ushort4 d[4], u[4], nd[4], nu[4];
            {
                const size_t bb = (size_t)eid[w * 8] * 256;
#pragma unroll
                for (int i = 0; i < 4; ++i) { d[i] = de4[bb + i * 64 + lane]; u[i] = ue4[bb + i * 64 + lane]; }
            }
#pragma unroll
            for (int jj = 0; jj < 8; ++jj) {
                if (jj < 7) {
                    const size_t bb = (size_t)eid[w * 8 + jj + 1] * 256;
#pragma unroll
                    for (int i = 0; i < 4; ++i) { nd[i] = de4[bb + i * 64 + lane]; nu[i] = ue4[bb + i * 64 + lane]; }
                }
                float s = 0.f;
#pragma unroll
                for (int i = 0; i < 4; ++i)
                    s += h[i].x * bf2f(d[i].x) + h[i].y * bf2f(d[i].y)
                       + h[i].z * bf2f(d[i].z) + h[i].w * bf2f(d[i].w);
#pragma unroll
                for (int m = 1; m < 64; m <<= 1) s += __shfl_xor(s, m);
                const float c = (s / (1.f + __expf(-s))) * wl[w * 8 + jj];
#pragma unroll
                for (int i = 0; i < 4; ++i) {
                    acc[i].x += c * bf2f(u[i].x); acc[i].y += c * bf2f(u[i].y);
                    acc[i].z += c * bf2f(u[i].z); acc[i].w += c * bf2f(u[i].w);
                }
                if (jj < 7) {
#pragma unroll
                    for (int i = 0; i < 4; ++i) { d[i] = nd[i]; u[i] = nu[i]; }
                }
            }
        } else {
            const float4* de4 = (const float4*)de_tab;
            const float4* ue4 = (const float4*)ue_tab;
            float4 d[4], u[4], nd[4], nu[4];
            {
                const size_t bb = (size_t)eid[w * 8] * 256;
#pragma unroll
                for (int i = 0; i < 4; ++i) { d[i] = de4[bb + i * 64 + lane]; u[i] = ue4[bb + i * 64 + lane]; }
            }
#pragma unroll
            for (int jj = 0; jj < 8; ++jj) {
                if (jj < 7) {
                    const size_t bb = (size_t)eid[w * 8 + jj + 1] * 256;
#pragma unroll
                    for (int i = 0; i < 4; ++i) { nd[i] = de4[bb + i * 64 + lane]; nu[i] = ue4[bb + i * 64 + lane]; }
                }
                float s = 0.f;
#pragma unroll
                for (int i = 0; i < 4; ++i)
                    s += h[i].x * d[i].x + h[i].y * d[i].y + h[i].z * d[i].z + h[i].w * d[i].w;
#pragma unroll
                for (int m = 1; m < 64; m <<= 1) s += __shfl_xor(s, m);
                const float c = (s / (1.f + __expf(-s))) * wl[w * 8 + jj];
#pragma unroll
                for (int i = 0; i < 4; ++i) {
                    acc[i].x += c * u[i].x; acc[i].y += c * u[i].y;
                    acc[i].z += c * u[i].z; acc[i].w += c * u[i].w;
                }
                if (jj < 7) {
#pragma unroll
                    for (int i = 0; i < 4; ++i) { d[i] = nd[i]; u[i] = nu[i]; }
                }
            }
        }

#pragma unroll
        for (int i = 0; i < 4; ++i) partial[w][i * 64 + lane] = acc[i];
        __syncthreads();

        const float4 p0 = partial[0][tid], p1 = partial[1][tid];
        const float4 p2 = partial[2][tid], p3 = partial[3][tid];
        float4 o;
        o.x = p0.x + p1.x + p2.x + p3.x;
        o.y = p0.y + p1.y + p2.y + p3.y;
        o.z = p0.z + p1.z + p2.z + p3.z;
        o.w = p0.w + p1.w + p2.w + p3.w;
        ((float4*)estate)[(size_t)t * 256 + tid] = o;
    }
}

// ---------------------------------------------------------------------------
extern "C" void kernel_launch(void* const* d_in, const int* in_sizes, int n_in,
                              void* d_out, int out_size, void* d_ws, size_t ws_size,
                              hipStream_t stream) {
    (void)in_sizes; (void)n_in; (void)out_size;
    const float* hidden = (const float*)d_in[0];
    const float* wq     = (const float*)d_in[1];
    const float* keys   = (const float*)d_in[2];
    const float* down_e = (const float*)d_in[3];
    const float* up_e   = (const float*)d_in[4];
    const float* wgate  = (const float*)d_in[5];
    const float* wup    = (const float*)d_in[6];
    const float* wdown  = (const float*)d_in[7];
    float* out = (float*)d_out;
    char* ws = (char*)d_ws;

    // workspace layout: EXACT round-13/14 (passed).
    ushort_t* hb  = (ushort_t*)(ws);                     // 4 MB
    ushort_t* wqb = (ushort_t*)(ws + (4u << 20));        // 0.5 MB
    ushort_t* wgb = (ushort_t*)(ws + (4608u << 10));     // 4 MB
    ushort_t* wub = (ushort_t*)(ws + (8704u << 10));     // 4 MB
    ushort_t* wdb = (ushort_t*)(ws + (12800u << 10));    // 4 MB
    float*    q   = (float*)   (ws + (16896u << 10));    // 2 MB
    ushort_t* act = (ushort_t*)(ws + (18944u << 10));    // 8 MB (raw u, then act)
    ushort_t* g   = (ushort_t*)(ws + (27136u << 10));    // 8 MB
    float*    wgt = (float*)   (ws + (35328u << 10));    // 0.25 MB
    int*     eidx = (int*)     (ws + (35584u << 10));    // 0.25 MB  (end 35.84 MB)
    ushort_t* deb = (ushort_t*)(ws + 36700160u);         // 32 MB
    ushort_t* ueb = (ushort_t*)(ws + 70254592u);         // 32 MB (end 103809024)
    float* estate = out;                                 // 8 MB, in d_out

    const bool bf16t = ws_size >= 103809024ull;          // host-side, deterministic

    convert_all<<<4224, 256, 0, stream>>>(hidden, wq, wgate, wup, wdown,
                                          hb, wqb, wgb, wub, wdb);

    // 1) q = hidden @ wq^T  (2048 x 256 x 1024), f32 out for routing
    mfma_gemm<64, 64, 2, 2, 2, 2, 0><<<dim3(4, 32), 256, 0, stream>>>(
        hb, wqb, nullptr, q, TOKENS, 256, DIM);

    // 2) routing (rank-based, standalone)
    topk_kernel<<<TOKENS, 256, 0, stream>>>(q, keys, eidx, wgt);

    if (bf16t) {
        // 2b) expert tables -> bf16 (standalone streaming, full occupancy)
        conv_tables<<<16384, 256, 0, stream>>>(down_e, up_e, deb, ueb);
        // 3+4+5 FUSED) g/u GEMMs || experts (bf16 tables) -> out
        fused3_kernel<1><<<3072, 256, 0, stream>>>(
            hb, wgb, wub, g, act, hidden, deb, ueb, eidx, wgt, estate);
    } else {
        fused3_kernel<0><<<3072, 256, 0, stream>>>(
            hb, wgb, wub, g, act, hidden, down_e, up_e, eidx, wgt, estate);
    }

    // 4b) act = silu(g) * u, in-place on the u buffer
    silu_mul_inplace<<<2048, 256, 0, stream>>>(g, act);
    // 6) out = act @ wdown^T + out(=estate)
    mfma_gemm<64, 64, 2, 2, 2, 2, 2><<<dim3(16, 32), 256, 0, stream>>>(
        act, wdb, estate, out, TOKENS, DIM, INTER);
}

// Round 16
// 189.408 us; speedup vs baseline: 1.6012x; 1.4981x over previous
//
#include <hip/hip_runtime.h>
#include <hip/hip_bf16.h>
#include <math.h>

// ---------------------------------------------------------------------------
// DogeCDMoE round 16: routing restructured. R15 isolated topk at 140us, 94%
// stalled on per-wave redundant q/keys global loads. Fix: sims are a batched
// GEMM -> (1) sim_gemm: MFMA (qgemm geometry, runtime strides, K=32 single
// step) writes sims[t][h][p][128] f32; (2) topk_select: per-wave rank
// selection from a coalesced 1KB sim row (R14's verified tie-order logic,
// no q/keys loads, no barriers). qgemm emits bf16 q (EPI3); keys join
// convert_all. conv_tables stays standalone (R14 coupling lesson).
// ---------------------------------------------------------------------------

#define TOKENS 2048
#define DIM    1024
#define INTER  2048
#define NKEYS  128
#define TOPK   8
#define HEADS  4

typedef unsigned short ushort_t;
typedef __attribute__((ext_vector_type(8))) short bf16x8;
typedef __attribute__((ext_vector_type(4))) float f32x4;

__device__ __forceinline__ float bf2f(ushort_t u) {
    unsigned int x = (unsigned int)u << 16;
    float f; __builtin_memcpy(&f, &x, 4); return f;
}
__device__ __forceinline__ ushort_t f2bf_rne(float f) {
    unsigned int x; __builtin_memcpy(&x, &f, 4);
    x += 0x7fffu + ((x >> 16) & 1u);
    return (ushort_t)(x >> 16);
}
__device__ __forceinline__ void gload_lds16(const void* g, void* l) {
    __builtin_amdgcn_global_load_lds(
        (const __attribute__((address_space(1))) unsigned int*)g,
        (__attribute__((address_space(3))) unsigned int*)l, 16, 0, 0);
}

// ---------------- fused f32 -> bf16 (RNE): 5 tensors + keys -----------------
__global__ __launch_bounds__(256) void convert_all(
    const float* __restrict__ h,  const float* __restrict__ wq,
    const float* __restrict__ wg, const float* __restrict__ wu,
    const float* __restrict__ wd, const float* __restrict__ keys,
    ushort_t* __restrict__ hb,  ushort_t* __restrict__ wqb,
    ushort_t* __restrict__ wgb, ushort_t* __restrict__ wub,
    ushort_t* __restrict__ wdb, ushort_t* __restrict__ kb) {
    const int i = blockIdx.x * 256 + threadIdx.x;
    const float* src; ushort_t* dst; int off;
    if      (i <  262144) { src = h;    dst = hb;  off = i; }
    else if (i <  294912) { src = wq;   dst = wqb; off = i - 262144; }
    else if (i <  557056) { src = wg;   dst = wgb; off = i - 294912; }
    else if (i <  819200) { src = wu;   dst = wub; off = i - 557056; }
    else if (i < 1081344) { src = wd;   dst = wdb; off = i - 819200; }
    else                  { src = keys; dst = kb;  off = i - 1081344; }
    const float4* p = (const float4*)src + (size_t)off * 2;
    const float4 a = p[0], b = p[1];
    uint4 o;
    o.x = (unsigned)f2bf_rne(a.x) | ((unsigned)f2bf_rne(a.y) << 16);
    o.y = (unsigned)f2bf_rne(a.z) | ((unsigned)f2bf_rne(a.w) << 16);
    o.z = (unsigned)f2bf_rne(b.x) | ((unsigned)f2bf_rne(b.y) << 16);
    o.w = (unsigned)f2bf_rne(b.z) | ((unsigned)f2bf_rne(b.w) << 16);
    ((uint4*)dst)[off] = o;
}

// ---------------- expert-table f32 -> bf16, standalone streaming ------------
__global__ __launch_bounds__(256) void conv_tables(
    const float* __restrict__ de_f32, const float* __restrict__ ue_f32,
    ushort_t* __restrict__ deb, ushort_t* __restrict__ ueb) {
    const int id = blockIdx.x;                       // 0..16383
    const float* src = (id < 8192) ? de_f32 : ue_f32;
    ushort_t*    dst = (id < 8192) ? deb : ueb;
    const size_t off = (size_t)(id & 8191) * 2048 + threadIdx.x * 8;
    const float4* p = (const float4*)(src + off);
    const float4 a = p[0], b = p[1];
    uint4 o;
    o.x = (unsigned)f2bf_rne(a.x) | ((unsigned)f2bf_rne(a.y) << 16);
    o.y = (unsigned)f2bf_rne(a.z) | ((unsigned)f2bf_rne(a.w) << 16);
    o.z = (unsigned)f2bf_rne(b.x) | ((unsigned)f2bf_rne(b.y) << 16);
    o.w = (unsigned)f2bf_rne(b.z) | ((unsigned)f2bf_rne(b.w) << 16);
    *(uint4*)(dst + off) = o;
}

// ---------------- bf16 MFMA GEMM: C[M,N] = A[M,K] @ B[N,K]^T ----------------
// EPI 0: f32 = acc | 1: bf16 = silu(extra_bf16)*acc | 2: f32 = acc+extra_f32
// EPI 3: bf16 = acc
template<int BM, int BN, int WR, int WC, int FM, int FN, int EPI>
__global__ __launch_bounds__(256) void mfma_gemm(const ushort_t* __restrict__ A,
                                                 const ushort_t* __restrict__ B,
                                                 const void* __restrict__ extra,
                                                 void* __restrict__ Cout,
                                                 int M, int N, int K) {
    static_assert(WR * WC == 4 && WR * FM * 16 == BM && WC * FN * 16 == BN, "geom");
    __shared__ ushort_t As[BM * 32];
    __shared__ ushort_t Bs[BN * 32];
    const int tid = threadIdx.x;
    const int w = tid >> 6, lane = tid & 63;
    const int wr = w / WC, wc = w % WC;
    const int m0 = blockIdx.y * BM, n0 = blockIdx.x * BN;

    const int srow = (w << 4) + (lane >> 2);
    const int scol = (lane & 3) << 3;
    const ushort_t* Ag = &A[(size_t)(m0 + srow) * K + scol];
    const ushort_t* Bg = &B[(size_t)(n0 + srow) * K + scol];
    ushort_t* Al = &As[w << 9];
    ushort_t* Bl = &Bs[w << 9];

    const int frow = lane & 15;
    const int fcol = (lane >> 4) << 3;
    const ushort_t* Afr = &As[(size_t)(wr * FM * 16 + frow) * 32 + fcol];
    const ushort_t* Bfr = &Bs[(size_t)(wc * FN * 16 + frow) * 32 + fcol];

    f32x4 acc[FM][FN];
#pragma unroll
    for (int i = 0; i < FM; ++i)
#pragma unroll
        for (int j = 0; j < FN; ++j) acc[i][j] = (f32x4){0.f, 0.f, 0.f, 0.f};

    for (int k0 = 0; k0 < K; k0 += 32) {
        __syncthreads();
#pragma unroll
        for (int i = 0; i < BM / 64; ++i)
            gload_lds16(Ag + (size_t)i * 64 * K + k0, Al + i * 2048);
#pragma unroll
        for (int i = 0; i < BN / 64; ++i)
            gload_lds16(Bg + (size_t)i * 64 * K + k0, Bl + i * 2048);
        __syncthreads();

        bf16x8 af[FM], bfv[FN];
#pragma unroll
        for (int i = 0; i < FM; ++i) af[i] = *(const bf16x8*)(Afr + i * 512);
#pragma unroll
        for (int j = 0; j < FN; ++j) bfv[j] = *(const bf16x8*)(Bfr + j * 512);
#pragma unroll
        for (int i = 0; i < FM; ++i)
#pragma unroll
            for (int j = 0; j < FN; ++j)
                acc[i][j] = __builtin_amdgcn_mfma_f32_16x16x32_bf16(
                    af[i], bfv[j], acc[i][j], 0, 0, 0);
    }

    const int crow0 = m0 + wr * FM * 16 + ((lane >> 4) << 2);
    const int ccol0 = n0 + wc * FN * 16 + (lane & 15);
#pragma unroll
    for (int i = 0; i < FM; ++i)
#pragma unroll
        for (int j = 0; j < FN; ++j)
#pragma unroll
            for (int r = 0; r < 4; ++r) {
                const size_t off = (size_t)(crow0 + i * 16 + r) * N + ccol0 + j * 16;
                float v = acc[i][j][r];
                if (EPI == 1) {
                    const float gg = bf2f(((const ushort_t*)extra)[off]);
                    v *= gg / (1.f + __expf(-gg));
                    ((ushort_t*)Cout)[off] = f2bf_rne(v);
                } else if (EPI == 2) {
                    ((float*)Cout)[off] = v + ((const float*)extra)[off];
                } else if (EPI == 3) {
                    ((ushort_t*)Cout)[off] = f2bf_rne(v);
                } else {
                    ((float*)Cout)[off] = v;
                }
            }
}

// ---------------- sim GEMM: sims[t][h][p][128] = qb-slice @ kb-slice^T ------
// grid (2, 32, 8): z = p*4+h... z -> h = z&3, p = z>>2. M-tile 64, N-tile 64,
// K = 32 (single MFMA step). A = qb + p*128 + h*32, lda=256.
// B row k at kb + h*8192 + p*32 + k*64 (ldb=64). C f32 row stride 1024.
__global__ __launch_bounds__(256) void sim_gemm(const ushort_t* __restrict__ qb,
                                                const ushort_t* __restrict__ kb,
                                                float* __restrict__ sims) {
    __shared__ ushort_t As[64 * 32];
    __shared__ ushort_t Bs[64 * 32];
    const int tid = threadIdx.x;
    const int w = tid >> 6, lane = tid & 63;
    const int wr = w >> 1, wc = w & 1;               // 2x2 waves
    const int m0 = blockIdx.y * 64, n0 = blockIdx.x * 64;
    const int h = blockIdx.z & 3, p = blockIdx.z >> 2;

    const int srow = (w << 4) + (lane >> 2);
    const int scol = (lane & 3) << 3;
    const ushort_t* Ag = &qb[(size_t)(m0 + srow) * 256 + p * 128 + h * 32 + scol];
    const ushort_t* Bg = &kb[(size_t)h * 8192 + p * 32 + (size_t)(n0 + srow) * 64 + scol];
    gload_lds16(Ag, &As[w << 9]);
    gload_lds16(Bg, &Bs[w << 9]);
    __syncthreads();

    const int frow = lane & 15;
    const int fcol = (lane >> 4) << 3;
    const ushort_t* Afr = &As[(size_t)(wr * 32 + frow) * 32 + fcol];
    const ushort_t* Bfr = &Bs[(size_t)(wc * 32 + frow) * 32 + fcol];

    f32x4 acc[2][2];
#pragma unroll
    for (int i = 0; i < 2; ++i)
#pragma unroll
        for (int j = 0; j < 2; ++j) acc[i][j] = (f32x4){0.f, 0.f, 0.f, 0.f};

    bf16x8 af[2], bfv[2];
#pragma unroll
    for (int i = 0; i < 2; ++i) af[i] = *(const bf16x8*)(Afr + i * 512);
#pragma unroll
    for (int j = 0; j < 2; ++j) bfv[j] = *(const bf16x8*)(Bfr + j * 512);
#pragma unroll
    for (int i = 0; i < 2; ++i)
#pragma unroll
        for (int j = 0; j < 2; ++j)
            acc[i][j] = __builtin_amdgcn_mfma_f32_16x16x32_bf16(
                af[i], bfv[j], acc[i][j], 0, 0, 0);

    const int crow0 = m0 + wr * 32 + ((lane >> 4) << 2);
    const int ccol0 = n0 + wc * 32 + (lane & 15);
#pragma unroll
    for (int i = 0; i < 2; ++i)
#pragma unroll
        for (int j = 0; j < 2; ++j)
#pragma unroll
            for (int r = 0; r < 4; ++r)
                sims[(size_t)(crow0 + i * 16 + r) * 1024 + h * 256 + p * 128
                     + ccol0 + j * 16] = acc[i][j][r];
}

// ---------------- topk_select: rank-based, sims from memory -----------------
// Block 256 = 4 waves; wave = head; t = blockIdx.x. Wave loads its 256-f32
// sim row coalesced (1KB), ranks in LDS (R14-verified tie order: value desc,
// index asc; combine tie -> lower position). No cross-wave sync needed.
__global__ __launch_bounds__(256) void topk_select(const float* __restrict__ sims,
                                                   int* __restrict__ eidx,
                                                   float* __restrict__ ewgt) {
    __shared__ float sm[HEADS][256];
    __shared__ float txv[HEADS][8];
    __shared__ int   txi[HEADS][8];
    __shared__ float tyv[HEADS][8];
    __shared__ int   tyi[HEADS][8];
    __shared__ float comb[HEADS][64];
    __shared__ float tfv[HEADS][8];
    __shared__ int   tfi[HEADS][8];
    const int t = blockIdx.x;
    const int head = threadIdx.x >> 6;
    const int lane = threadIdx.x & 63;

    const float4 v = *(const float4*)&sims[(size_t)t * 1024 + head * 256 + lane * 4];
    *(float4*)&sm[head][lane * 4] = v;
    // wave-local LDS: lockstep write-before-read within the wave

    const int isY = lane >= 32;
    const float* base = &sm[head][isY ? 128 : 0];
    const int gi = (lane * 4) - (isY ? 128 : 0);     // codebook-local index
    int r0 = 0, r1 = 0, r2 = 0, r3 = 0;
#pragma unroll
    for (int j = 0; j < 128; j += 4) {
        const float4 s = *(const float4*)&base[j];
        r0 += (s.x > v.x) | ((s.x == v.x) & (j + 0 < gi + 0));
        r0 += (s.y > v.x) | ((s.y == v.x) & (j + 1 < gi + 0));
        r0 += (s.z > v.x) | ((s.z == v.x) & (j + 2 < gi + 0));
        r0 += (s.w > v.x) | ((s.w == v.x) & (j + 3 < gi + 0));
        r1 += (s.x > v.y) | ((s.x == v.y) & (j + 0 < gi + 1));
        r1 += (s.y > v.y) | ((s.y == v.y) & (j + 1 < gi + 1));
        r1 += (s.z > v.y) | ((s.z == v.y) & (j + 2 < gi + 1));
        r1 += (s.w > v.y) | ((s.w == v.y) & (j + 3 < gi + 1));
        r2 += (s.x > v.z) | ((s.x == v.z) & (j + 0 < gi + 2));
        r2 += (s.y > v.z) | ((s.y == v.z) & (j + 1 < gi + 2));
        r2 += (s.z > v.z) | ((s.z == v.z) & (j + 2 < gi + 2));
        r2 += (s.w > v.z) | ((s.w == v.z) & (j + 3 < gi + 2));
        r3 += (s.x > v.w) | ((s.x == v.w) & (j + 0 < gi + 3));
        r3 += (s.y > v.w) | ((s.y == v.w) & (j + 1 < gi + 3));
        r3 += (s.z > v.w) | ((s.z == v.w) & (j + 2 < gi + 3));
        r3 += (s.w > v.w) | ((s.w == v.w) & (j + 3 < gi + 3));
    }
    if (!isY) {
        if (r0 < TOPK) { txv[head][r0] = v.x; txi[head][r0] = gi + 0; }
        if (r1 < TOPK) { txv[head][r1] = v.y; txi[head][r1] = gi + 1; }
        if (r2 < TOPK) { txv[head][r2] = v.z; txi[head][r2] = gi + 2; }
        if (r3 < TOPK) { txv[head][r3] = v.w; txi[head][r3] = gi + 3; }
    } else {
        if (r0 < TOPK) { tyv[head][r0] = v.x; tyi[head][r0] = gi + 0; }
        if (r1 < TOPK) { tyv[head][r1] = v.y; tyi[head][r1] = gi + 1; }
        if (r2 < TOPK) { tyv[head][r2] = v.z; tyi[head][r2] = gi + 2; }
        if (r3 < TOPK) { tyv[head][r3] = v.w; tyi[head][r3] = gi + 3; }
    }

    // cartesian combine: a = lane>>3 (x rank), b = lane&7 (y rank)
    const float cv = txv[head][lane >> 3] + tyv[head][lane & 7];
    const int   ci = txi[head][lane >> 3] * NKEYS + tyi[head][lane & 7];
    comb[head][lane] = cv;

    int cr = 0;
#pragma unroll
    for (int j = 0; j < 64; j += 4) {
        const float4 s = *(const float4*)&comb[head][j];
        cr += (s.x > cv) | ((s.x == cv) & (j + 0 < lane));
        cr += (s.y > cv) | ((s.y == cv) & (j + 1 < lane));
        cr += (s.z > cv) | ((s.z == cv) & (j + 2 < lane));
        cr += (s.w > cv) | ((s.w == cv) & (j + 3 < lane));
    }
    if (cr < TOPK) { tfv[head][cr] = cv; tfi[head][cr] = ci; }

    float f[8];
#pragma unroll
    for (int j = 0; j < 8; ++j) f[j] = tfv[head][j];
    float mx = f[0];
#pragma unroll
    for (int j = 1; j < 8; ++j) mx = fmaxf(mx, f[j]);
    float ssum = 0.f;
#pragma unroll
    for (int j = 0; j < 8; ++j) ssum += expf(f[j] - mx);
    if (lane < 8) {
        eidx[t * 32 + head * 8 + lane] = tfi[head][lane];
        ewgt[t * 32 + head * 8 + lane] = expf(f[lane] - mx) / ssum;
    }
}

// ---------------- act[i] = silu(g[i]) * u[i], in-place on u -----------------
__global__ __launch_bounds__(256) void silu_mul_inplace(const ushort_t* __restrict__ g,
                                                        ushort_t* __restrict__ u) {
    const int i = blockIdx.x * 256 + threadIdx.x;
    const uint4 gv = ((const uint4*)g)[i];
    const uint4 uv = ((const uint4*)u)[i];
    const unsigned gw[4] = {gv.x, gv.y, gv.z, gv.w};
    const unsigned uw[4] = {uv.x, uv.y, uv.z, uv.w};
    unsigned ow[4];
#pragma unroll
    for (int j = 0; j < 4; ++j) {
        const float g0 = bf2f((ushort_t)(gw[j] & 0xffff));
        const float g1 = bf2f((ushort_t)(gw[j] >> 16));
        const float u0 = bf2f((ushort_t)(uw[j] & 0xffff));
        const float u1 = bf2f((ushort_t)(uw[j] >> 16));
        const float v0 = g0 / (1.f + __expf(-g0)) * u0;
        const float v1 = g1 / (1.f + __expf(-g1)) * u1;
        ow[j] = (unsigned)f2bf_rne(v0) | ((unsigned)f2bf_rne(v1) << 16);
    }
    ((uint4*)u)[i] = (uint4){ow[0], ow[1], ow[2], ow[3]};
}

// ---------------- FUSED: gate GEMM + up GEMM + experts blocks ---------------
__global__ __launch_bounds__(256) void fused3_kernel(
    const ushort_t* __restrict__ A,  const ushort_t* __restrict__ Bgate,
    const ushort_t* __restrict__ Bup, ushort_t* __restrict__ G,
    ushort_t* __restrict__ U,
    const float* __restrict__ hs, const ushort_t* __restrict__ de_tab,
    const ushort_t* __restrict__ ue_tab, const int* __restrict__ eidx,
    const float* __restrict__ ewgt, float* __restrict__ estate) {
    __shared__ __align__(16) char smem[16896];
    const int b = blockIdx.x;
    const int tid = threadIdx.x;
    const int w = tid >> 6, lane = tid & 63;
    const int r6 = b % 6;

    if (r6 == 2 || r6 == 5) {
        const ushort_t* B = (r6 == 2) ? Bgate : Bup;
        ushort_t*      C  = (r6 == 2) ? G : U;
        const int id = b / 6;
        const int m0 = (id >> 4) * 64, n0 = (id & 15) * 128;
        const int N = INTER, K = DIM;
        ushort_t* As = (ushort_t*)smem;
        ushort_t* Bs = (ushort_t*)(smem + 4096);
        const int wc = w;
        const int srow = (w << 4) + (lane >> 2);
        const int scol = (lane & 3) << 3;
        const ushort_t* Ag = &A[(size_t)(m0 + srow) * K + scol];
        const ushort_t* Bg = &B[(size_t)(n0 + srow) * K + scol];
        ushort_t* Al = &As[w << 9];
        ushort_t* Bl = &Bs[w << 9];
        const int frow = lane & 15;
        const int fcol = (lane >> 4) << 3;
        const ushort_t* Afr = &As[(size_t)frow * 32 + fcol];
        const ushort_t* Bfr = &Bs[(size_t)(wc * 32 + frow) * 32 + fcol];

        f32x4 acc[4][2];
#pragma unroll
        for (int i = 0; i < 4; ++i)
#pragma unroll
            for (int j = 0; j < 2; ++j) acc[i][j] = (f32x4){0.f, 0.f, 0.f, 0.f};

        for (int k0 = 0; k0 < K; k0 += 32) {
            __syncthreads();
            gload_lds16(Ag + k0, Al);
#pragma unroll
            for (int i = 0; i < 2; ++i)
                gload_lds16(Bg + (size_t)i * 64 * K + k0, Bl + i * 2048);
            __syncthreads();

            bf16x8 af[4], bfv[2];
#pragma unroll
            for (int i = 0; i < 4; ++i) af[i] = *(const bf16x8*)(Afr + i * 512);
#pragma unroll
            for (int j = 0; j < 2; ++j) bfv[j] = *(const bf16x8*)(Bfr + j * 512);
#pragma unroll
            for (int i = 0; i < 4; ++i)
#pragma unroll
                for (int j = 0; j < 2; ++j)
                    acc[i][j] = __builtin_amdgcn_mfma_f32_16x16x32_bf16(
                        af[i], bfv[j], acc[i][j], 0, 0, 0);
        }

        const int crow0 = m0 + ((lane >> 4) << 2);
        const int ccol0 = n0 + wc * 32 + (lane & 15);
#pragma unroll
        for (int i = 0; i < 4; ++i)
#pragma unroll
            for (int j = 0; j < 2; ++j)
#pragma unroll
                for (int r = 0; r < 4; ++r) {
                    const size_t off = (size_t)(crow0 + i * 16 + r) * N + ccol0 + j * 16;
                    C[off] = f2bf_rne(acc[i][j][r]);
                }
    } else {
        const int t = (b / 6) * 4 + r6 - (r6 > 2 ? 1 : 0);
        float4 (*partial)[256] = (float4(*)[256])smem;
        int*   eid = (int*)(smem + 16384);
        float* wl  = (float*)(smem + 16512);

        if (tid < 32) { eid[tid] = eidx[t * 32 + tid]; wl[tid] = ewgt[t * 32 + tid]; }

        const float4* hs4 = (const float4*)hs + (size_t)t * 256;
        float4 h[4];
#pragma unroll
        for (int i = 0; i < 4; ++i) h[i] = hs4[i * 64 + lane];
        __syncthreads();

        float4 acc[4];
#pragma unroll
        for (int i = 0; i < 4; ++i) acc[i] = (float4){0.f, 0.f, 0.f, 0.f};

        const ushort4* de4 = (const ushort4*)de_tab;
        const ushort4* ue4 = (const ushort4*)ue_tab;
        ushort4 d[4], u[4], nd[4], nu[4];
        {
            const size_t bb = (size_t)eid[w * 8] * 256;
#pragma unroll
            for (int i = 0; i < 4; ++i) { d[i] = de4[bb + i * 64 + lane]; u[i] = ue4[bb + i * 64 + lane]; }
        }
#pragma unroll
        for (int jj = 0; jj < 8; ++jj) {
            if (jj < 7) {
                const size_t bb = (size_t)eid[w * 8 + jj + 1] * 256;
#pragma unroll
                for (int i = 0; i < 4; ++i) { nd[i] = de4[bb + i * 64 + lane]; nu[i] = ue4[bb + i * 64 + lane]; }
            }
            float s = 0.f;
#pragma unroll
            for (int i = 0; i < 4; ++i)
                s += h[i].x * bf2f(d[i].x) + h[i].y * bf2f(d[i].y)
                   + h[i].z * bf2f(d[i].z) + h[i].w * bf2f(d[i].w);
#pragma unroll
            for (int m = 1; m < 64; m <<= 1) s += __shfl_xor(s, m);
            const float c = (s / (1.f + __expf(-s))) * wl[w * 8 + jj];
#pragma unroll
            for (int i = 0; i < 4; ++i) {
                acc[i].x += c * bf2f(u[i].x); acc[i].y += c * bf2f(u[i].y);
                acc[i].z += c * bf2f(u[i].z); acc[i].w += c * bf2f(u[i].w);
            }
            if (jj < 7) {
#pragma unroll
                for (int i = 0; i < 4; ++i) { d[i] = nd[i]; u[i] = nu[i]; }
            }
        }

#pragma unroll
        for (int i = 0; i < 4; ++i) partial[w][i * 64 + lane] = acc[i];
        __syncthreads();

        const float4 p0 = partial[0][tid], p1 = partial[1][tid];
        const float4 p2 = partial[2][tid], p3 = partial[3][tid];
        float4 o;
        o.x = p0.x + p1.x + p2.x + p3.x;
        o.y = p0.y + p1.y + p2.y + p3.y;
        o.z = p0.z + p1.z + p2.z + p3.z;
        o.w = p0.w + p1.w + p2.w + p3.w;
        ((float4*)estate)[(size_t)t * 256 + tid] = o;
    }
}

// ---------------------------------------------------------------------------
extern "C" void kernel_launch(void* const* d_in, const int* in_sizes, int n_in,
                              void* d_out, int out_size, void* d_ws, size_t ws_size,
                              hipStream_t stream) {
    (void)in_sizes; (void)n_in; (void)out_size; (void)ws_size;
    const float* hidden = (const float*)d_in[0];
    const float* wq     = (const float*)d_in[1];
    const float* keys   = (const float*)d_in[2];
    const float* down_e = (const float*)d_in[3];
    const float* up_e   = (const float*)d_in[4];
    const float* wgate  = (const float*)d_in[5];
    const float* wup    = (const float*)d_in[6];
    const float* wdown  = (const float*)d_in[7];
    float* out = (float*)d_out;
    char* ws = (char*)d_ws;

    // workspace layout (R13-proven 104MB footprint; ws_size >= 103809024
    // verified by R13/R14/R15 passing with the bf16t branch engaged).
    // qb+kb live in the old 2MB q region; sims (8MB f32) lives in the act
    // region (act written by fused3 only after topk_select consumed sims).
    ushort_t* hb  = (ushort_t*)(ws);                     // 4 MB
    ushort_t* wqb = (ushort_t*)(ws + (4u << 20));        // 0.5 MB
    ushort_t* wgb = (ushort_t*)(ws + (4608u << 10));     // 4 MB
    ushort_t* wub = (ushort_t*)(ws + (8704u << 10));     // 4 MB
    ushort_t* wdb = (ushort_t*)(ws + (12800u << 10));    // 4 MB
    ushort_t* qb  = (ushort_t*)(ws + (16896u << 10));    // 1 MB   (old q region)
    ushort_t* kb  = (ushort_t*)(ws + (17920u << 10));    // 64 KB  (old q region)
    ushort_t* act = (ushort_t*)(ws + (18944u << 10));    // 8 MB (sims, then u/act)
    float*   sims = (float*)act;                         // alias (pre-fused3)
    ushort_t* g   = (ushort_t*)(ws + (27136u << 10));    // 8 MB
    float*    wgt = (float*)   (ws + (35328u << 10));    // 0.25 MB
    int*     eidx = (int*)     (ws + (35584u << 10));    // 0.25 MB
    ushort_t* deb = (ushort_t*)(ws + 36700160u);         // 32 MB
    ushort_t* ueb = (ushort_t*)(ws + 70254592u);         // 32 MB
    float* estate = out;                                 // 8 MB, in d_out

    // 0) conversions (5 tensors + keys)
    convert_all<<<4240, 256, 0, stream>>>(hidden, wq, wgate, wup, wdown, keys,
                                          hb, wqb, wgb, wub, wdb, kb);
    // 0b) expert tables -> bf16 (standalone streaming)
    conv_tables<<<16384, 256, 0, stream>>>(down_e, up_e, deb, ueb);
    // 1) qb = hidden @ wq^T -> bf16 (2048 x 256 x 1024)
    mfma_gemm<64, 64, 2, 2, 2, 2, 3><<<dim3(4, 32), 256, 0, stream>>>(
        hb, wqb, nullptr, qb, TOKENS, 256, DIM);
    // 2a) sims[t][h][p][128] = qb-slice @ kb-slice^T (8 groups, K=32)
    sim_gemm<<<dim3(2, 32, 8), 256, 0, stream>>>(qb, kb, sims);
    // 2b) routing: rank-based select on coalesced sim rows
    topk_select<<<TOKENS, 256, 0, stream>>>(sims, eidx, wgt);
    // 3+4+5 FUSED) g/u GEMMs || experts (bf16 tables) -> out
    fused3_kernel<<<3072, 256, 0, stream>>>(
        hb, wgb, wub, g, act, hidden, deb, ueb, eidx, wgt, estate);
    // 4b) act = silu(g) * u, in-place on the u buffer
    silu_mul_inplace<<<2048, 256, 0, stream>>>(g, act);
    // 6) out = act @ wdown^T + out(=estate)
    mfma_gemm<64, 64, 2, 2, 2, 2, 2><<<dim3(16, 32), 256, 0, stream>>>(
        act, wdb, estate, out, TOKENS, DIM, INTER);
}